// Round 8
// baseline (1048.812 us; speedup 1.0000x reference)
//
#include <hip/hip_runtime.h>
#include <hip/hip_cooperative_groups.h>
#include <math.h>

namespace cg = cooperative_groups;

// LGNGuard: 3-layer guarded LightGCN propagation + sigmoid(U @ I^T) scoring.
// Single persistent cooperative kernel: CSR build, bf16 table, 3 layers of
// {cos+rowsum -> prune+EMA+SpMM(+fused norms,+rowsum-dbuf-zero)}, selected-row
// accumulation, 64x64-tile final GEMM. grid.sync() between dependent phases.

#define DD 64
typedef unsigned int u32;

__device__ __forceinline__ float bflo(u32 u) { return __uint_as_float(u << 16); }
__device__ __forceinline__ float bfhi(u32 u) { return __uint_as_float(u & 0xFFFF0000u); }
__device__ __forceinline__ u32 bfpk(float lo, float hi) {   // RNE pack
    u32 a = __float_as_uint(lo), b = __float_as_uint(hi);
    a = (a + 0x7FFFu + ((a >> 16) & 1u)) >> 16;
    b = (b + 0x7FFFu + ((b >> 16) & 1u)) & 0xFFFF0000u;
    return a | b;
}
__device__ __forceinline__ void unp16(uint4 q0, uint4 q1, float* f) {
    f[0]=bflo(q0.x); f[1]=bfhi(q0.x); f[2]=bflo(q0.y); f[3]=bfhi(q0.y);
    f[4]=bflo(q0.z); f[5]=bfhi(q0.z); f[6]=bflo(q0.w); f[7]=bfhi(q0.w);
    f[8]=bflo(q1.x); f[9]=bfhi(q1.x); f[10]=bflo(q1.y); f[11]=bfhi(q1.y);
    f[12]=bflo(q1.z); f[13]=bfhi(q1.z); f[14]=bflo(q1.w); f[15]=bfhi(q1.w);
}

struct Params {
    const int *users, *items;
    const float *ue, *ie, *Wp, *bp;
    const int *src, *dst;
    const float *adj;
    u32 *tabA, *tabB;
    int2 *ent;
    int *cidx;
    float *norms, *rsA, *rsB, *cosc, *memc, *acc;
    int *deg, *rp, *rank, *partial;
    float *out;
    int BU, BI, NU, Nn, E, EH, M;
};

// ---- cos + rowsums over USER rows (each undirected edge once), unroll x4 ----
__device__ __forceinline__ void cos_phase(const Params& P, const u32* tab,
                                          float* rsum, int gt, int gs) {
    const int NU4 = P.NU * 4;
    for (int x = gt; x < NU4; x += gs) {
        int r = x >> 2, l4 = x & 3;
        int p0 = P.rp[r], p1 = P.rp[r + 1];
        const uint4* ap = (const uint4*)(tab + (size_t)r * 32 + l4 * 8);
        float A[16];
        unp16(ap[0], ap[1], A);
        float nr = P.norms[r];
        float rs = 0.f;
        int p = p0;
        for (; p + 4 <= p1; p += 4) {
            int d0 = P.ent[p].x, d1 = P.ent[p+1].x, d2 = P.ent[p+2].x, d3 = P.ent[p+3].x;
            const uint4* q0 = (const uint4*)(tab + (size_t)d0 * 32 + l4 * 8);
            const uint4* q1 = (const uint4*)(tab + (size_t)d1 * 32 + l4 * 8);
            const uint4* q2 = (const uint4*)(tab + (size_t)d2 * 32 + l4 * 8);
            const uint4* q3 = (const uint4*)(tab + (size_t)d3 * 32 + l4 * 8);
            uint4 b00 = q0[0], b01 = q0[1];
            uint4 b10 = q1[0], b11 = q1[1];
            uint4 b20 = q2[0], b21 = q2[1];
            uint4 b30 = q3[0], b31 = q3[1];
            float n0 = P.norms[d0], n1 = P.norms[d1];
            float n2 = P.norms[d2], n3 = P.norms[d3];
            float B[16];
            float dt0 = 0.f, dt1 = 0.f, dt2 = 0.f, dt3 = 0.f;
            unp16(b00, b01, B);
#pragma unroll
            for (int i = 0; i < 16; ++i) dt0 += A[i] * B[i];
            unp16(b10, b11, B);
#pragma unroll
            for (int i = 0; i < 16; ++i) dt1 += A[i] * B[i];
            unp16(b20, b21, B);
#pragma unroll
            for (int i = 0; i < 16; ++i) dt2 += A[i] * B[i];
            unp16(b30, b31, B);
#pragma unroll
            for (int i = 0; i < 16; ++i) dt3 += A[i] * B[i];
            dt0 += __shfl_xor(dt0, 1, 64); dt0 += __shfl_xor(dt0, 2, 64);
            dt1 += __shfl_xor(dt1, 1, 64); dt1 += __shfl_xor(dt1, 2, 64);
            dt2 += __shfl_xor(dt2, 1, 64); dt2 += __shfl_xor(dt2, 2, 64);
            dt3 += __shfl_xor(dt3, 1, 64); dt3 += __shfl_xor(dt3, 2, 64);
            float c0 = dt0 / fmaxf(nr * n0, 1e-8f);
            float c1 = dt1 / fmaxf(nr * n1, 1e-8f);
            float c2 = dt2 / fmaxf(nr * n2, 1e-8f);
            float c3 = dt3 / fmaxf(nr * n3, 1e-8f);
            if (l4 == 0) {
                P.cosc[p]   = c0; atomicAdd(&rsum[d0], fabsf(c0));
                P.cosc[p+1] = c1; atomicAdd(&rsum[d1], fabsf(c1));
                P.cosc[p+2] = c2; atomicAdd(&rsum[d2], fabsf(c2));
                P.cosc[p+3] = c3; atomicAdd(&rsum[d3], fabsf(c3));
            }
            rs += fabsf(c0) + fabsf(c1) + fabsf(c2) + fabsf(c3);
        }
        for (; p < p1; ++p) {
            int d = P.ent[p].x;
            const uint4* q = (const uint4*)(tab + (size_t)d * 32 + l4 * 8);
            uint4 b0 = q[0], b1 = q[1];
            float B[16];
            unp16(b0, b1, B);
            float dot = 0.f;
#pragma unroll
            for (int i = 0; i < 16; ++i) dot += A[i] * B[i];
            dot += __shfl_xor(dot, 1, 64);
            dot += __shfl_xor(dot, 2, 64);
            float c = dot / fmaxf(nr * P.norms[d], 1e-8f);
            if (l4 == 0) {
                P.cosc[p] = c;
                atomicAdd(&rsum[d], fabsf(c));
            }
            rs += fabsf(c);
        }
        if (l4 == 0) rsum[r] = rs;
    }
}

#define EDGE_BODY(cv, rd, mp, ty, bA, bB, DO_MEM, pp)                       \
    {                                                                       \
        float a = __int_as_float(ty);                                       \
        float rdg = rd > 0.f ? rd : 1.f;                                    \
        float c  = cv / rsg;                                                \
        float cr = cv / rdg;                                                \
        float z  = w0 * c + w1 * cr + bb;                                   \
        float kept = (z > 0.f) ? c : 0.f;                                   \
        float m = 0.5f * mp + 0.5f * kept;                                  \
        if (DO_MEM && l4 == 0) P.memc[pp] = m;                              \
        float g = m * a;                                                    \
        unp16(bA, bB, B);                                                   \
        _Pragma("unroll")                                                   \
        for (int i = 0; i < 16; ++i) a16[i] += g * B[i];                    \
    }

// ---- fused normalize+prune+EMA+SpMM all rows, + next-layer norms, unroll x4 ----
__device__ __forceinline__ void spmm_phase(const Params& P, const u32* tab,
                                           u32* otab, const float* rsum,
                                           float* rsnext, int useAdj,
                                           int gt, int gs) {
    for (int i = gt; i < P.Nn; i += gs) rsnext[i] = 0.f;   // zero other rowsum buf
    float w0 = P.Wp[0], w1 = P.Wp[1], bb = P.bp[0];
    const int Nn4 = P.Nn * 4;
    for (int x = gt; x < Nn4; x += gs) {
        int r = x >> 2, l4 = x & 3;
        int p0 = P.rp[r], p1 = P.rp[r + 1];
        bool isU = (r < P.NU);
        float rs  = rsum[r];
        float rsg = rs > 0.f ? rs : 1.f;
        float a16[16];
#pragma unroll
        for (int i = 0; i < 16; ++i) a16[i] = 0.f;
        int p = p0;
        for (; p + 4 <= p1; p += 4) {
            int2 t0 = P.ent[p], t1 = P.ent[p+1], t2 = P.ent[p+2], t3 = P.ent[p+3];
            int c0i = isU ? p   : P.cidx[p   - P.EH];
            int c1i = isU ? p+1 : P.cidx[p+1 - P.EH];
            int c2i = isU ? p+2 : P.cidx[p+2 - P.EH];
            int c3i = isU ? p+3 : P.cidx[p+3 - P.EH];
            const uint4* q0 = (const uint4*)(tab + (size_t)t0.x * 32 + l4 * 8);
            const uint4* q1 = (const uint4*)(tab + (size_t)t1.x * 32 + l4 * 8);
            const uint4* q2 = (const uint4*)(tab + (size_t)t2.x * 32 + l4 * 8);
            const uint4* q3 = (const uint4*)(tab + (size_t)t3.x * 32 + l4 * 8);
            uint4 b00 = q0[0], b01 = q0[1];
            uint4 b10 = q1[0], b11 = q1[1];
            uint4 b20 = q2[0], b21 = q2[1];
            uint4 b30 = q3[0], b31 = q3[1];
            float cv0 = P.cosc[c0i], cv1 = P.cosc[c1i];
            float cv2 = P.cosc[c2i], cv3 = P.cosc[c3i];
            float rd0 = rsum[t0.x], rd1 = rsum[t1.x];
            float rd2 = rsum[t2.x], rd3 = rsum[t3.x];
            float mp0 = useAdj ? __int_as_float(t0.y) : P.memc[p];
            float mp1 = useAdj ? __int_as_float(t1.y) : P.memc[p+1];
            float mp2 = useAdj ? __int_as_float(t2.y) : P.memc[p+2];
            float mp3 = useAdj ? __int_as_float(t3.y) : P.memc[p+3];
            float B[16];
            EDGE_BODY(cv0, rd0, mp0, t0.y, b00, b01, 1, p)
            EDGE_BODY(cv1, rd1, mp1, t1.y, b10, b11, 1, p+1)
            EDGE_BODY(cv2, rd2, mp2, t2.y, b20, b21, 1, p+2)
            EDGE_BODY(cv3, rd3, mp3, t3.y, b30, b31, 1, p+3)
        }
        for (; p < p1; ++p) {
            int2 t0 = P.ent[p];
            int ci = isU ? p : P.cidx[p - P.EH];
            const uint4* q = (const uint4*)(tab + (size_t)t0.x * 32 + l4 * 8);
            uint4 b0 = q[0], b1 = q[1];
            float cv = P.cosc[ci];
            float rd = rsum[t0.x];
            float mp = useAdj ? __int_as_float(t0.y) : P.memc[p];
            float B[16];
            EDGE_BODY(cv, rd, mp, t0.y, b0, b1, 1, p)
        }
        // fused next-layer norm (from f32 pre-round values)
        float s = 0.f;
#pragma unroll
        for (int i = 0; i < 16; ++i) s += a16[i] * a16[i];
        s += __shfl_xor(s, 1, 64);
        s += __shfl_xor(s, 2, 64);
        if (l4 == 0) P.norms[r] = sqrtf(s);
        uint4 o0, o1;
        o0.x = bfpk(a16[0], a16[1]);   o0.y = bfpk(a16[2], a16[3]);
        o0.z = bfpk(a16[4], a16[5]);   o0.w = bfpk(a16[6], a16[7]);
        o1.x = bfpk(a16[8], a16[9]);   o1.y = bfpk(a16[10], a16[11]);
        o1.z = bfpk(a16[12], a16[13]); o1.w = bfpk(a16[14], a16[15]);
        uint4* op = (uint4*)(otab + (size_t)r * 32 + l4 * 8);
        op[0] = o0;
        op[1] = o1;
    }
}

// ---- final layer: SpMM only for selected rows, accumulate into acc ----
__device__ __forceinline__ void sel_spmm_phase(const Params& P, const u32* tab,
                                               const float* rsum, int gt, int gs) {
    float w0 = P.Wp[0], w1 = P.Wp[1], bb = P.bp[0];
    const int S4 = (P.BU + P.BI) * 4;
    for (int x = gt; x < S4; x += gs) {
        int q_ = x >> 2, l4 = x & 3;
        int r = (q_ < P.BU) ? P.users[q_] : (P.NU + P.items[q_ - P.BU]);
        int p0 = P.rp[r], p1 = P.rp[r + 1];
        bool isU = (r < P.NU);
        float rs  = rsum[r];
        float rsg = rs > 0.f ? rs : 1.f;
        float a16[16];
#pragma unroll
        for (int i = 0; i < 16; ++i) a16[i] = 0.f;
        int p = p0;
        for (; p + 4 <= p1; p += 4) {
            int2 t0 = P.ent[p], t1 = P.ent[p+1], t2 = P.ent[p+2], t3 = P.ent[p+3];
            int c0i = isU ? p   : P.cidx[p   - P.EH];
            int c1i = isU ? p+1 : P.cidx[p+1 - P.EH];
            int c2i = isU ? p+2 : P.cidx[p+2 - P.EH];
            int c3i = isU ? p+3 : P.cidx[p+3 - P.EH];
            const uint4* q0 = (const uint4*)(tab + (size_t)t0.x * 32 + l4 * 8);
            const uint4* q1 = (const uint4*)(tab + (size_t)t1.x * 32 + l4 * 8);
            const uint4* q2 = (const uint4*)(tab + (size_t)t2.x * 32 + l4 * 8);
            const uint4* q3 = (const uint4*)(tab + (size_t)t3.x * 32 + l4 * 8);
            uint4 b00 = q0[0], b01 = q0[1];
            uint4 b10 = q1[0], b11 = q1[1];
            uint4 b20 = q2[0], b21 = q2[1];
            uint4 b30 = q3[0], b31 = q3[1];
            float cv0 = P.cosc[c0i], cv1 = P.cosc[c1i];
            float cv2 = P.cosc[c2i], cv3 = P.cosc[c3i];
            float rd0 = rsum[t0.x], rd1 = rsum[t1.x];
            float rd2 = rsum[t2.x], rd3 = rsum[t3.x];
            float mp0 = P.memc[p],   mp1 = P.memc[p+1];
            float mp2 = P.memc[p+2], mp3 = P.memc[p+3];
            float B[16];
            EDGE_BODY(cv0, rd0, mp0, t0.y, b00, b01, 0, p)
            EDGE_BODY(cv1, rd1, mp1, t1.y, b10, b11, 0, p)
            EDGE_BODY(cv2, rd2, mp2, t2.y, b20, b21, 0, p)
            EDGE_BODY(cv3, rd3, mp3, t3.y, b30, b31, 0, p)
        }
        for (; p < p1; ++p) {
            int2 t0 = P.ent[p];
            int ci = isU ? p : P.cidx[p - P.EH];
            const uint4* q = (const uint4*)(tab + (size_t)t0.x * 32 + l4 * 8);
            uint4 b0 = q[0], b1 = q[1];
            float cv = P.cosc[ci];
            float rd = rsum[t0.x];
            float mp = P.memc[p];
            float B[16];
            EDGE_BODY(cv, rd, mp, t0.y, b0, b1, 0, p)
        }
        float4* av = (float4*)P.acc;
#pragma unroll
        for (int k = 0; k < 4; ++k) {
            float4 o = av[(size_t)q_ * 16 + l4 * 4 + k];
            o.x += a16[k * 4 + 0]; o.y += a16[k * 4 + 1];
            o.z += a16[k * 4 + 2]; o.w += a16[k * 4 + 3];
            av[(size_t)q_ * 16 + l4 * 4 + k] = o;
        }
    }
}

// ---- add bf16-table selected rows into acc ----
__device__ __forceinline__ void acc_upd_phase(const Params& P, const u32* tab,
                                              int gt, int gs) {
    const int S4 = (P.BU + P.BI) * 4;
    for (int x = gt; x < S4; x += gs) {
        int q_ = x >> 2, l4 = x & 3;
        int node = (q_ < P.BU) ? P.users[q_] : (P.NU + P.items[q_ - P.BU]);
        const uint4* p = (const uint4*)(tab + (size_t)node * 32 + l4 * 8);
        float f[16];
        unp16(p[0], p[1], f);
        float4* av = (float4*)P.acc;
#pragma unroll
        for (int k = 0; k < 4; ++k) {
            float4 o = av[(size_t)q_ * 16 + l4 * 4 + k];
            o.x += f[k * 4 + 0]; o.y += f[k * 4 + 1];
            o.z += f[k * 4 + 2]; o.w += f[k * 4 + 3];
            av[(size_t)q_ * 16 + l4 * 4 + k] = o;
        }
    }
}

__global__ __launch_bounds__(256, 4) void mega_k(Params P) {
    __shared__ float shf[2 * 64 * 65];
    int* shi = (int*)shf;
    cg::grid_group grd = cg::this_grid();
    const int t = threadIdx.x, b = blockIdx.x, nb = gridDim.x;
    const int gt = b * 256 + t, gs = nb * 256;

    // P0: zero deg
    for (int i = gt; i < P.M; i += gs) P.deg[i] = 0;
    grd.sync();

    // P1: histogram + rank
    for (int e = gt; e < P.E; e += gs) P.rank[e] = atomicAdd(&P.deg[P.src[e]], 1);
    grd.sync();

    // P2: scan within 1024-chunks
    int nch = (P.M + 1023) >> 10;
    for (int chunk = b; chunk < nch; chunk += nb) {
        int base = chunk << 10;
        int i0 = base + t * 4;
        int v0 = (i0 + 0 < P.M) ? P.deg[i0 + 0] : 0;
        int v1 = (i0 + 1 < P.M) ? P.deg[i0 + 1] : 0;
        int v2 = (i0 + 2 < P.M) ? P.deg[i0 + 2] : 0;
        int v3 = (i0 + 3 < P.M) ? P.deg[i0 + 3] : 0;
        int tsum = v0 + v1 + v2 + v3;
        shi[t] = tsum;
        __syncthreads();
        for (int off = 1; off < 256; off <<= 1) {
            int x = (t >= off) ? shi[t - off] : 0;
            __syncthreads();
            shi[t] += x;
            __syncthreads();
        }
        int texcl = shi[t] - tsum;
        if (i0 + 0 < P.M) P.rp[i0 + 0] = texcl;
        if (i0 + 1 < P.M) P.rp[i0 + 1] = texcl + v0;
        if (i0 + 2 < P.M) P.rp[i0 + 2] = texcl + v0 + v1;
        if (i0 + 3 < P.M) P.rp[i0 + 3] = texcl + v0 + v1 + v2;
        if (t == 255) P.partial[chunk] = shi[255];
        __syncthreads();
    }
    grd.sync();

    // P3: scan partials (block 0)
    if (b == 0) {
        int v = (t < nch) ? P.partial[t] : 0;
        shi[t] = v;
        __syncthreads();
        for (int off = 1; off < 256; off <<= 1) {
            int x = (t >= off) ? shi[t - off] : 0;
            __syncthreads();
            shi[t] += x;
            __syncthreads();
        }
        if (t < nch) P.partial[t] = shi[t] - v;
    }
    grd.sync();

    // P4: add partials
    for (int i = gt; i < P.M; i += gs) P.rp[i] += P.partial[i >> 10];
    grd.sync();

    // P5: scatter + cvt(+norms0) + zero rsA + acc_init
    for (int e = gt; e < P.EH; e += gs) {
        int u = P.src[e], i = P.dst[e];
        int ab = __float_as_int(P.adj[e]);
        int posU = P.rp[u] + P.rank[e];
        int posI = P.rp[i] + P.rank[e + P.EH];
        P.ent[posU] = make_int2(i, ab);
        P.ent[posI] = make_int2(u, ab);
        P.cidx[posI - P.EH] = posU;
    }
    for (int i = gt; i < P.Nn; i += gs) P.rsA[i] = 0.f;
    for (int x = gt; x < P.Nn * 4; x += gs) {
        int node = x >> 2, l4 = x & 3;
        const float4* srow = (node < P.NU)
            ? (const float4*)(P.ue + (size_t)node * DD)
            : (const float4*)(P.ie + (size_t)(node - P.NU) * DD);
        float f[16];
#pragma unroll
        for (int k = 0; k < 4; ++k) {
            float4 v = srow[l4 * 4 + k];
            f[k*4+0] = v.x; f[k*4+1] = v.y; f[k*4+2] = v.z; f[k*4+3] = v.w;
        }
        uint4 o0, o1;
        o0.x = bfpk(f[0], f[1]);   o0.y = bfpk(f[2], f[3]);
        o0.z = bfpk(f[4], f[5]);   o0.w = bfpk(f[6], f[7]);
        o1.x = bfpk(f[8], f[9]);   o1.y = bfpk(f[10], f[11]);
        o1.z = bfpk(f[12], f[13]); o1.w = bfpk(f[14], f[15]);
        uint4* op = (uint4*)(P.tabA + (size_t)node * 32 + l4 * 8);
        op[0] = o0;
        op[1] = o1;
        float fb[16];
        unp16(o0, o1, fb);
        float s = 0.f;
#pragma unroll
        for (int i = 0; i < 16; ++i) s += fb[i] * fb[i];
        s += __shfl_xor(s, 1, 64);
        s += __shfl_xor(s, 2, 64);
        if (l4 == 0) P.norms[node] = sqrtf(s);
    }
    {   // acc_init from f32 inputs
        const int S4 = (P.BU + P.BI) * 4;
        for (int x = gt; x < S4; x += gs) {
            int q_ = x >> 2, l4 = x & 3;
            int node = (q_ < P.BU) ? P.users[q_] : (P.NU + P.items[q_ - P.BU]);
            const float4* srow = (node < P.NU)
                ? (const float4*)(P.ue + (size_t)node * DD)
                : (const float4*)(P.ie + (size_t)(node - P.NU) * DD);
            float4* av = (float4*)P.acc;
#pragma unroll
            for (int k = 0; k < 4; ++k)
                av[(size_t)q_ * 16 + l4 * 4 + k] = srow[l4 * 4 + k];
        }
    }
    grd.sync();

    // ---- layer 0 ----
    cos_phase(P, P.tabA, P.rsA, gt, gs);
    grd.sync();
    spmm_phase(P, P.tabA, P.tabB, P.rsA, P.rsB, 1, gt, gs);
    grd.sync();
    // ---- layer 1 ----
    acc_upd_phase(P, P.tabB, gt, gs);
    cos_phase(P, P.tabB, P.rsB, gt, gs);
    grd.sync();
    spmm_phase(P, P.tabB, P.tabA, P.rsB, P.rsA, 0, gt, gs);
    grd.sync();
    // ---- layer 2 ----
    acc_upd_phase(P, P.tabA, gt, gs);
    cos_phase(P, P.tabA, P.rsA, gt, gs);
    grd.sync();
    sel_spmm_phase(P, P.tabA, P.rsA, gt, gs);
    grd.sync();

    // final GEMM: sigmoid(dot(accU,accI)/16), 64x64 tiles
    float* Us = shf;
    float* Is = shf + 64 * 65;
    int tilesX = P.BI / 64;
    int tiles = tilesX * (P.BU / 64);
    for (int tile = b; tile < tiles; tile += nb) {
        int i0 = (tile / tilesX) * 64, j0 = (tile % tilesX) * 64;
#pragma unroll
        for (int i = 0; i < 4; ++i) {
            int f4 = t + i * 256;
            int r = f4 >> 4, c4 = (f4 & 15) * 4;
            float4 u4 = *(const float4*)&P.acc[(size_t)(i0 + r) * DD + c4];
            float4 v4 = *(const float4*)&P.acc[(size_t)(P.BU + j0 + r) * DD + c4];
            Us[r * 65 + c4 + 0] = u4.x; Us[r * 65 + c4 + 1] = u4.y;
            Us[r * 65 + c4 + 2] = u4.z; Us[r * 65 + c4 + 3] = u4.w;
            Is[r * 65 + c4 + 0] = v4.x; Is[r * 65 + c4 + 1] = v4.y;
            Is[r * 65 + c4 + 2] = v4.z; Is[r * 65 + c4 + 3] = v4.w;
        }
        __syncthreads();
        int tx = t & 15, ty = t >> 4;
        float s[4][4];
#pragma unroll
        for (int i = 0; i < 4; ++i)
#pragma unroll
            for (int j = 0; j < 4; ++j) s[i][j] = 0.f;
        for (int k = 0; k < 64; ++k) {
            float u[4], v[4];
#pragma unroll
            for (int i = 0; i < 4; ++i) u[i] = Us[(ty * 4 + i) * 65 + k];
#pragma unroll
            for (int j = 0; j < 4; ++j) v[j] = Is[(tx * 4 + j) * 65 + k];
#pragma unroll
            for (int i = 0; i < 4; ++i)
#pragma unroll
                for (int j = 0; j < 4; ++j) s[i][j] += u[i] * v[j];
        }
#pragma unroll
        for (int i = 0; i < 4; ++i) {
            float4 o;
            o.x = 1.f / (1.f + expf(-s[i][0] * 0.0625f));
            o.y = 1.f / (1.f + expf(-s[i][1] * 0.0625f));
            o.z = 1.f / (1.f + expf(-s[i][2] * 0.0625f));
            o.w = 1.f / (1.f + expf(-s[i][3] * 0.0625f));
            *(float4*)&P.out[(size_t)(i0 + ty * 4 + i) * P.BI + j0 + tx * 4] = o;
        }
        __syncthreads();
    }
}

// ================= launch =================

extern "C" void kernel_launch(void* const* d_in, const int* in_sizes, int n_in,
                              void* d_out, int out_size, void* d_ws, size_t ws_size,
                              hipStream_t stream) {
    Params P;
    P.users = (const int*)d_in[0];
    P.items = (const int*)d_in[1];
    P.ue    = (const float*)d_in[2];
    P.ie    = (const float*)d_in[3];
    P.Wp    = (const float*)d_in[4];
    P.bp    = (const float*)d_in[5];
    P.src   = (const int*)d_in[6];
    P.dst   = (const int*)d_in[7];
    P.adj   = (const float*)d_in[9];

    P.BU = in_sizes[0];
    P.BI = in_sizes[1];
    P.NU = in_sizes[2] / DD;
    int NI = in_sizes[3] / DD;
    P.Nn = P.NU + NI;
    P.E  = in_sizes[6];
    P.EH = P.E / 2;
    P.M  = P.Nn + 1;
    int Mp = (P.M + 3) & ~3;

    P.tabA   = (u32*)d_ws;                                   // Nn*32
    P.tabB   = P.tabA + (size_t)P.Nn * 32;                   // Nn*32
    P.ent    = (int2*)(P.tabB + (size_t)P.Nn * 32);          // E
    P.cidx   = (int*)(P.ent + P.E);                          // EH
    P.norms  = (float*)(P.cidx + P.EH);                      // Nn
    P.rsA    = P.norms + P.Nn;                               // Nn
    P.rsB    = P.rsA + P.Nn;                                 // Nn
    P.cosc   = P.rsB + P.Nn;                                 // EH
    P.memc   = P.cosc + P.EH;                                // E
    P.acc    = P.memc + P.E;                                 // (BU+BI)*64
    P.deg    = (int*)(P.acc + (size_t)(P.BU + P.BI) * DD);   // Mp
    P.rp     = P.deg + Mp;                                   // Mp
    P.rank   = P.rp + Mp;                                    // E
    P.partial= P.rank + P.E;                                 // 256
    P.out    = (float*)d_out;

    int bpc = 0;
    hipError_t err = hipOccupancyMaxActiveBlocksPerMultiprocessor(&bpc, mega_k, 256, 0);
    if (err != hipSuccess || bpc < 1) bpc = 1;
    long grid = (long)bpc * 256;           // 256 CUs on MI355X
    if (grid > 1024) grid = 1024;

    void* args[] = { (void*)&P };
    hipLaunchCooperativeKernel(mega_k, dim3((int)grid), dim3(256), args, 0, stream);
}

// Round 9
// 342.400 us; speedup vs baseline: 3.0631x; 3.0631x over previous
//
#include <hip/hip_runtime.h>
#include <math.h>

// LGNGuard: 3-layer guarded LightGCN propagation + sigmoid(U @ I^T) scoring.
// Multi-kernel (no grid.sync — coop kernel regressed 3x). CSR by src
// (atomic-free scatter); cos once per undirected edge; prune+EMA fused into
// SpMM; layer-3 SpMM only for selected rows. BF16 table, f32 math, x4 unroll.
// Fusions: norms in cvt/spmm epilogue; rowsum zeroing in epilogues; acc_upd
// piggybacked on cos launches (block-role split).

#define DD 64
typedef unsigned int u32;

__device__ __forceinline__ float bflo(u32 u) { return __uint_as_float(u << 16); }
__device__ __forceinline__ float bfhi(u32 u) { return __uint_as_float(u & 0xFFFF0000u); }
__device__ __forceinline__ u32 bfpk(float lo, float hi) {   // RNE pack
    u32 a = __float_as_uint(lo), b = __float_as_uint(hi);
    a = (a + 0x7FFFu + ((a >> 16) & 1u)) >> 16;
    b = (b + 0x7FFFu + ((b >> 16) & 1u)) & 0xFFFF0000u;
    return a | b;
}
__device__ __forceinline__ void unp16(uint4 q0, uint4 q1, float* f) {
    f[0]=bflo(q0.x); f[1]=bfhi(q0.x); f[2]=bflo(q0.y); f[3]=bfhi(q0.y);
    f[4]=bflo(q0.z); f[5]=bfhi(q0.z); f[6]=bflo(q0.w); f[7]=bfhi(q0.w);
    f[8]=bflo(q1.x); f[9]=bfhi(q1.x); f[10]=bflo(q1.y); f[11]=bfhi(q1.y);
    f[12]=bflo(q1.z); f[13]=bfhi(q1.z); f[14]=bflo(q1.w); f[15]=bfhi(q1.w);
}

// ================= CSR build =================

__global__ __launch_bounds__(256) void hist_k(const int* __restrict__ src,
                                              int* __restrict__ deg,
                                              int* __restrict__ rank, int E) {
    int e = blockIdx.x * blockDim.x + threadIdx.x;
    if (e < E) rank[e] = atomicAdd(&deg[src[e]], 1);
}

__global__ __launch_bounds__(256) void scan1_k(const int* __restrict__ in,
                                               int* __restrict__ out,
                                               int* __restrict__ partial, int M) {
    __shared__ int sh[256];
    int base = blockIdx.x * 1024;
    int t = threadIdx.x;
    int i0 = base + t * 4;
    int v0 = (i0 + 0 < M) ? in[i0 + 0] : 0;
    int v1 = (i0 + 1 < M) ? in[i0 + 1] : 0;
    int v2 = (i0 + 2 < M) ? in[i0 + 2] : 0;
    int v3 = (i0 + 3 < M) ? in[i0 + 3] : 0;
    int tsum = v0 + v1 + v2 + v3;
    sh[t] = tsum;
    __syncthreads();
    for (int off = 1; off < 256; off <<= 1) {
        int x = (t >= off) ? sh[t - off] : 0;
        __syncthreads();
        sh[t] += x;
        __syncthreads();
    }
    int texcl = sh[t] - tsum;
    if (i0 + 0 < M) out[i0 + 0] = texcl;
    if (i0 + 1 < M) out[i0 + 1] = texcl + v0;
    if (i0 + 2 < M) out[i0 + 2] = texcl + v0 + v1;
    if (i0 + 3 < M) out[i0 + 3] = texcl + v0 + v1 + v2;
    if (t == 255) partial[blockIdx.x] = sh[255];
}

__global__ __launch_bounds__(256) void scan2_k(int* __restrict__ partial, int nc) {
    __shared__ int sh[256];
    int t = threadIdx.x;
    int v = (t < nc) ? partial[t] : 0;
    sh[t] = v;
    __syncthreads();
    for (int off = 1; off < 256; off <<= 1) {
        int x = (t >= off) ? sh[t - off] : 0;
        __syncthreads();
        sh[t] += x;
        __syncthreads();
    }
    if (t < nc) partial[t] = sh[t] - v;
}

__global__ __launch_bounds__(256) void scan3_k(int* __restrict__ out,
                                               const int* __restrict__ partial, int M) {
    int i = blockIdx.x * blockDim.x + threadIdx.x;
    if (i < M) out[i] += partial[i >> 10];
}

// one thread per UNDIRECTED edge; no atomics
__global__ __launch_bounds__(256) void scatter_k(const int* __restrict__ src,
                                                 const int* __restrict__ dst,
                                                 const float* __restrict__ adj,
                                                 const int* __restrict__ rp,
                                                 const int* __restrict__ rank,
                                                 int2* __restrict__ ent,
                                                 int* __restrict__ cidx, int EH) {
    int e = blockIdx.x * blockDim.x + threadIdx.x;
    if (e >= EH) return;
    int u = src[e], i = dst[e];
    int ab = __float_as_int(adj[e]);
    int posU = rp[u] + rank[e];
    int posI = rp[i] + rank[e + EH];
    ent[posU] = make_int2(i, ab);
    ent[posI] = make_int2(u, ab);
    cidx[posI - EH] = posU;
}

// ================= bf16 table + norms + rs-zero + acc-init (fused) =================

__global__ __launch_bounds__(256) void cvt_fused_k(const float* __restrict__ ue,
                                                   const float* __restrict__ ie,
                                                   const int* __restrict__ users,
                                                   const int* __restrict__ items,
                                                   u32* __restrict__ tab,
                                                   float* __restrict__ norms,
                                                   float* __restrict__ rsA,
                                                   float* __restrict__ acc,
                                                   int NU, int Nn, int BU, int BI,
                                                   int cvtBlocks) {
    int b = blockIdx.x;
    if (b < cvtBlocks) {
        int x = b * 256 + threadIdx.x;
        if (x >= Nn * 4) return;
        int node = x >> 2, l4 = x & 3;
        const float4* srow = (node < NU)
            ? (const float4*)(ue + (size_t)node * DD)
            : (const float4*)(ie + (size_t)(node - NU) * DD);
        float f[16];
#pragma unroll
        for (int k = 0; k < 4; ++k) {
            float4 v = srow[l4 * 4 + k];
            f[k*4+0] = v.x; f[k*4+1] = v.y; f[k*4+2] = v.z; f[k*4+3] = v.w;
        }
        uint4 o0, o1;
        o0.x = bfpk(f[0], f[1]);   o0.y = bfpk(f[2], f[3]);
        o0.z = bfpk(f[4], f[5]);   o0.w = bfpk(f[6], f[7]);
        o1.x = bfpk(f[8], f[9]);   o1.y = bfpk(f[10], f[11]);
        o1.z = bfpk(f[12], f[13]); o1.w = bfpk(f[14], f[15]);
        uint4* op = (uint4*)(tab + (size_t)node * 32 + l4 * 8);
        op[0] = o0;
        op[1] = o1;
        float fb[16];
        unp16(o0, o1, fb);
        float s = 0.f;
#pragma unroll
        for (int i = 0; i < 16; ++i) s += fb[i] * fb[i];
        s += __shfl_xor(s, 1, 64);
        s += __shfl_xor(s, 2, 64);
        if (l4 == 0) {
            norms[node] = sqrtf(s);
            if (node >= NU) rsA[node] = 0.f;
        }
    } else {
        int x = (b - cvtBlocks) * 256 + threadIdx.x;
        if (x >= (BU + BI) * 4) return;
        int q_ = x >> 2, l4 = x & 3;
        int node = (q_ < BU) ? users[q_] : (NU + items[q_ - BU]);
        const float4* srow = (node < NU)
            ? (const float4*)(ue + (size_t)node * DD)
            : (const float4*)(ie + (size_t)(node - NU) * DD);
        float4* av = (float4*)acc;
#pragma unroll
        for (int k = 0; k < 4; ++k)
            av[(size_t)q_ * 16 + l4 * 4 + k] = srow[l4 * 4 + k];
    }
}

// ============ cos + rowsums over USER rows (+ optional acc_upd blocks) ============

__global__ __launch_bounds__(256) void cos_acc_k(const u32* __restrict__ tab,
                                                 const float* __restrict__ norms,
                                                 const int* __restrict__ rp,
                                                 const int2* __restrict__ ent,
                                                 float* __restrict__ cosc,
                                                 float* __restrict__ rowsum,
                                                 const int* __restrict__ users,
                                                 const int* __restrict__ items,
                                                 float* __restrict__ acc,
                                                 int NU, int BU, int BI,
                                                 int cosBlocks) {
    int b = blockIdx.x;
    if (b >= cosBlocks) {   // acc_upd role: add tab's selected rows into acc
        int x = (b - cosBlocks) * 256 + threadIdx.x;
        if (x >= (BU + BI) * 4) return;
        int q_ = x >> 2, l4 = x & 3;
        int node = (q_ < BU) ? users[q_] : (NU + items[q_ - BU]);
        const uint4* p = (const uint4*)(tab + (size_t)node * 32 + l4 * 8);
        float f[16];
        unp16(p[0], p[1], f);
        float4* av = (float4*)acc;
#pragma unroll
        for (int k = 0; k < 4; ++k) {
            float4 o = av[(size_t)q_ * 16 + l4 * 4 + k];
            o.x += f[k * 4 + 0]; o.y += f[k * 4 + 1];
            o.z += f[k * 4 + 2]; o.w += f[k * 4 + 3];
            av[(size_t)q_ * 16 + l4 * 4 + k] = o;
        }
        return;
    }
    int x = b * 256 + threadIdx.x;
    if (x >= NU * 4) return;
    int r = x >> 2, l4 = x & 3;
    int p0 = rp[r], p1 = rp[r + 1];
    const uint4* ap = (const uint4*)(tab + (size_t)r * 32 + l4 * 8);
    float A[16];
    unp16(ap[0], ap[1], A);
    float nr = norms[r];
    float rs = 0.f;
    int p = p0;
    for (; p + 4 <= p1; p += 4) {
        int d0 = ent[p].x, d1 = ent[p+1].x, d2 = ent[p+2].x, d3 = ent[p+3].x;
        const uint4* q0 = (const uint4*)(tab + (size_t)d0 * 32 + l4 * 8);
        const uint4* q1 = (const uint4*)(tab + (size_t)d1 * 32 + l4 * 8);
        const uint4* q2 = (const uint4*)(tab + (size_t)d2 * 32 + l4 * 8);
        const uint4* q3 = (const uint4*)(tab + (size_t)d3 * 32 + l4 * 8);
        uint4 b00 = q0[0], b01 = q0[1];
        uint4 b10 = q1[0], b11 = q1[1];
        uint4 b20 = q2[0], b21 = q2[1];
        uint4 b30 = q3[0], b31 = q3[1];
        float n0 = norms[d0], n1 = norms[d1], n2 = norms[d2], n3 = norms[d3];
        float B[16];
        float dt0 = 0.f, dt1 = 0.f, dt2 = 0.f, dt3 = 0.f;
        unp16(b00, b01, B);
#pragma unroll
        for (int i = 0; i < 16; ++i) dt0 += A[i] * B[i];
        unp16(b10, b11, B);
#pragma unroll
        for (int i = 0; i < 16; ++i) dt1 += A[i] * B[i];
        unp16(b20, b21, B);
#pragma unroll
        for (int i = 0; i < 16; ++i) dt2 += A[i] * B[i];
        unp16(b30, b31, B);
#pragma unroll
        for (int i = 0; i < 16; ++i) dt3 += A[i] * B[i];
        dt0 += __shfl_xor(dt0, 1, 64); dt0 += __shfl_xor(dt0, 2, 64);
        dt1 += __shfl_xor(dt1, 1, 64); dt1 += __shfl_xor(dt1, 2, 64);
        dt2 += __shfl_xor(dt2, 1, 64); dt2 += __shfl_xor(dt2, 2, 64);
        dt3 += __shfl_xor(dt3, 1, 64); dt3 += __shfl_xor(dt3, 2, 64);
        float c0 = dt0 / fmaxf(nr * n0, 1e-8f);
        float c1 = dt1 / fmaxf(nr * n1, 1e-8f);
        float c2 = dt2 / fmaxf(nr * n2, 1e-8f);
        float c3 = dt3 / fmaxf(nr * n3, 1e-8f);
        if (l4 == 0) {
            cosc[p]   = c0; atomicAdd(&rowsum[d0], fabsf(c0));
            cosc[p+1] = c1; atomicAdd(&rowsum[d1], fabsf(c1));
            cosc[p+2] = c2; atomicAdd(&rowsum[d2], fabsf(c2));
            cosc[p+3] = c3; atomicAdd(&rowsum[d3], fabsf(c3));
        }
        rs += fabsf(c0) + fabsf(c1) + fabsf(c2) + fabsf(c3);
    }
    for (; p < p1; ++p) {
        int d = ent[p].x;
        const uint4* q = (const uint4*)(tab + (size_t)d * 32 + l4 * 8);
        uint4 b0 = q[0], b1 = q[1];
        float B[16];
        unp16(b0, b1, B);
        float dot = 0.f;
#pragma unroll
        for (int i = 0; i < 16; ++i) dot += A[i] * B[i];
        dot += __shfl_xor(dot, 1, 64);
        dot += __shfl_xor(dot, 2, 64);
        float c = dot / fmaxf(nr * norms[d], 1e-8f);
        if (l4 == 0) {
            cosc[p] = c;
            atomicAdd(&rowsum[d], fabsf(c));
        }
        rs += fabsf(c);
    }
    if (l4 == 0) rowsum[r] = rs;
}

// ===== fused normalize+prune+EMA+SpMM all rows (+next norms, +rsnext zero) =====

__global__ __launch_bounds__(256) void spmm_fused_k(const u32* __restrict__ tab,
                                                    const int* __restrict__ rp,
                                                    const int2* __restrict__ ent,
                                                    const int* __restrict__ cidx,
                                                    const float* __restrict__ cosc,
                                                    const float* __restrict__ rowsum,
                                                    const float* __restrict__ Wp,
                                                    const float* __restrict__ bp,
                                                    float* __restrict__ memc, int useAdj,
                                                    u32* __restrict__ outtab,
                                                    float* __restrict__ norms,
                                                    float* __restrict__ rsnext,
                                                    int NU, int EH, int N) {
    int x = blockIdx.x * 256 + threadIdx.x;
    if (x >= N * 4) return;
    int r = x >> 2, l4 = x & 3;
    int p0 = rp[r], p1 = rp[r + 1];
    bool isU = (r < NU);
    float w0 = Wp[0], w1 = Wp[1], bb = bp[0];
    float rs  = rowsum[r];
    float rsg = rs > 0.f ? rs : 1.f;
    float a16[16];
#pragma unroll
    for (int i = 0; i < 16; ++i) a16[i] = 0.f;
    int p = p0;
    for (; p + 4 <= p1; p += 4) {
        int2 t0 = ent[p], t1 = ent[p+1], t2 = ent[p+2], t3 = ent[p+3];
        int c0i = isU ? p   : cidx[p   - EH];
        int c1i = isU ? p+1 : cidx[p+1 - EH];
        int c2i = isU ? p+2 : cidx[p+2 - EH];
        int c3i = isU ? p+3 : cidx[p+3 - EH];
        const uint4* q0 = (const uint4*)(tab + (size_t)t0.x * 32 + l4 * 8);
        const uint4* q1 = (const uint4*)(tab + (size_t)t1.x * 32 + l4 * 8);
        const uint4* q2 = (const uint4*)(tab + (size_t)t2.x * 32 + l4 * 8);
        const uint4* q3 = (const uint4*)(tab + (size_t)t3.x * 32 + l4 * 8);
        uint4 b00 = q0[0], b01 = q0[1];
        uint4 b10 = q1[0], b11 = q1[1];
        uint4 b20 = q2[0], b21 = q2[1];
        uint4 b30 = q3[0], b31 = q3[1];
        float cv0 = cosc[c0i], cv1 = cosc[c1i], cv2 = cosc[c2i], cv3 = cosc[c3i];
        float rd0 = rowsum[t0.x], rd1 = rowsum[t1.x];
        float rd2 = rowsum[t2.x], rd3 = rowsum[t3.x];
        float mp0 = useAdj ? __int_as_float(t0.y) : memc[p];
        float mp1 = useAdj ? __int_as_float(t1.y) : memc[p+1];
        float mp2 = useAdj ? __int_as_float(t2.y) : memc[p+2];
        float mp3 = useAdj ? __int_as_float(t3.y) : memc[p+3];
        float B[16];
#define EDGE(cv, rd, mp, ty, bA, bB, pp)                                    \
        {                                                                   \
            float a = __int_as_float(ty);                                   \
            float rdg = rd > 0.f ? rd : 1.f;                                \
            float c  = cv / rsg;                                            \
            float cr = cv / rdg;                                            \
            float z  = w0 * c + w1 * cr + bb;                               \
            float kept = (z > 0.f) ? c : 0.f;                               \
            float m = 0.5f * mp + 0.5f * kept;                              \
            if (l4 == 0) memc[pp] = m;                                      \
            float g = m * a;                                                \
            unp16(bA, bB, B);                                               \
            _Pragma("unroll")                                               \
            for (int i = 0; i < 16; ++i) a16[i] += g * B[i];                \
        }
        EDGE(cv0, rd0, mp0, t0.y, b00, b01, p)
        EDGE(cv1, rd1, mp1, t1.y, b10, b11, p+1)
        EDGE(cv2, rd2, mp2, t2.y, b20, b21, p+2)
        EDGE(cv3, rd3, mp3, t3.y, b30, b31, p+3)
    }
    for (; p < p1; ++p) {
        int2 t = ent[p];
        int ci = isU ? p : cidx[p - EH];
        const uint4* q = (const uint4*)(tab + (size_t)t.x * 32 + l4 * 8);
        uint4 b0 = q[0], b1 = q[1];
        float cv = cosc[ci];
        float rd = rowsum[t.x];
        float mp = useAdj ? __int_as_float(t.y) : memc[p];
        float B[16];
        EDGE(cv, rd, mp, t.y, b0, b1, p)
    }
#undef EDGE
    // fused next-layer norm + rsnext zeroing (item rows only get atomics)
    float s = 0.f;
#pragma unroll
    for (int i = 0; i < 16; ++i) s += a16[i] * a16[i];
    s += __shfl_xor(s, 1, 64);
    s += __shfl_xor(s, 2, 64);
    if (l4 == 0) {
        norms[r] = sqrtf(s);
        if (r >= NU) rsnext[r] = 0.f;
    }
    uint4 o0, o1;
    o0.x = bfpk(a16[0], a16[1]);   o0.y = bfpk(a16[2], a16[3]);
    o0.z = bfpk(a16[4], a16[5]);   o0.w = bfpk(a16[6], a16[7]);
    o1.x = bfpk(a16[8], a16[9]);   o1.y = bfpk(a16[10], a16[11]);
    o1.z = bfpk(a16[12], a16[13]); o1.w = bfpk(a16[14], a16[15]);
    uint4* op = (uint4*)(outtab + (size_t)r * 32 + l4 * 8);
    op[0] = o0;
    op[1] = o1;
}

// ===== final layer: SpMM only for selected rows, accumulate into acc =====

__global__ __launch_bounds__(256) void sel_spmm_k(const u32* __restrict__ tab,
                                                  const int* __restrict__ rp,
                                                  const int2* __restrict__ ent,
                                                  const int* __restrict__ cidx,
                                                  const float* __restrict__ cosc,
                                                  const float* __restrict__ rowsum,
                                                  const float* __restrict__ Wp,
                                                  const float* __restrict__ bp,
                                                  const float* __restrict__ memc,
                                                  const int* __restrict__ users,
                                                  const int* __restrict__ items,
                                                  float* __restrict__ acc,
                                                  int BU, int BI, int NU, int EH) {
    int x = blockIdx.x * 256 + threadIdx.x;
    if (x >= (BU + BI) * 4) return;
    int q_ = x >> 2, l4 = x & 3;
    int r = (q_ < BU) ? users[q_] : (NU + items[q_ - BU]);
    int p0 = rp[r], p1 = rp[r + 1];
    bool isU = (r < NU);
    float w0 = Wp[0], w1 = Wp[1], bb = bp[0];
    float rs  = rowsum[r];
    float rsg = rs > 0.f ? rs : 1.f;
    float a16[16];
#pragma unroll
    for (int i = 0; i < 16; ++i) a16[i] = 0.f;
    int p = p0;
    for (; p + 4 <= p1; p += 4) {
        int2 t0 = ent[p], t1 = ent[p+1], t2 = ent[p+2], t3 = ent[p+3];
        int c0i = isU ? p   : cidx[p   - EH];
        int c1i = isU ? p+1 : cidx[p+1 - EH];
        int c2i = isU ? p+2 : cidx[p+2 - EH];
        int c3i = isU ? p+3 : cidx[p+3 - EH];
        const uint4* q0 = (const uint4*)(tab + (size_t)t0.x * 32 + l4 * 8);
        const uint4* q1 = (const uint4*)(tab + (size_t)t1.x * 32 + l4 * 8);
        const uint4* q2 = (const uint4*)(tab + (size_t)t2.x * 32 + l4 * 8);
        const uint4* q3 = (const uint4*)(tab + (size_t)t3.x * 32 + l4 * 8);
        uint4 b00 = q0[0], b01 = q0[1];
        uint4 b10 = q1[0], b11 = q1[1];
        uint4 b20 = q2[0], b21 = q2[1];
        uint4 b30 = q3[0], b31 = q3[1];
        float cv0 = cosc[c0i], cv1 = cosc[c1i], cv2 = cosc[c2i], cv3 = cosc[c3i];
        float rd0 = rowsum[t0.x], rd1 = rowsum[t1.x];
        float rd2 = rowsum[t2.x], rd3 = rowsum[t3.x];
        float mm0 = memc[p], mm1 = memc[p+1], mm2 = memc[p+2], mm3 = memc[p+3];
        float B[16];
#define EDGES(cv, rd, mm, ty, bA, bB)                                       \
        {                                                                   \
            float a = __int_as_float(ty);                                   \
            float rdg = rd > 0.f ? rd : 1.f;                                \
            float c  = cv / rsg;                                            \
            float cr = cv / rdg;                                            \
            float z  = w0 * c + w1 * cr + bb;                               \
            float kept = (z > 0.f) ? c : 0.f;                               \
            float m = 0.5f * mm + 0.5f * kept;                              \
            float g = m * a;                                                \
            unp16(bA, bB, B);                                               \
            _Pragma("unroll")                                               \
            for (int i = 0; i < 16; ++i) a16[i] += g * B[i];                \
        }
        EDGES(cv0, rd0, mm0, t0.y, b00, b01)
        EDGES(cv1, rd1, mm1, t1.y, b10, b11)
        EDGES(cv2, rd2, mm2, t2.y, b20, b21)
        EDGES(cv3, rd3, mm3, t3.y, b30, b31)
    }
    for (; p < p1; ++p) {
        int2 t = ent[p];
        int ci = isU ? p : cidx[p - EH];
        const uint4* q = (const uint4*)(tab + (size_t)t.x * 32 + l4 * 8);
        uint4 b0 = q[0], b1 = q[1];
        float cv = cosc[ci];
        float rd = rowsum[t.x];
        float mm = memc[p];
        float B[16];
        EDGES(cv, rd, mm, t.y, b0, b1)
    }
#undef EDGES
    float4* av = (float4*)acc;
#pragma unroll
    for (int k = 0; k < 4; ++k) {
        float4 o = av[(size_t)q_ * 16 + l4 * 4 + k];
        o.x += a16[k * 4 + 0]; o.y += a16[k * 4 + 1];
        o.z += a16[k * 4 + 2]; o.w += a16[k * 4 + 3];
        av[(size_t)q_ * 16 + l4 * 4 + k] = o;
    }
}

// ================= final GEMM =================

__global__ __launch_bounds__(256) void final_gemm_k(const float* __restrict__ acc,
                                                    float* __restrict__ out,
                                                    int BU, int BI) {
    __shared__ float Us[64][65];
    __shared__ float Is[64][65];
    int t = threadIdx.x;
    int i0 = blockIdx.y * 64, j0 = blockIdx.x * 64;
#pragma unroll
    for (int i = 0; i < 4; ++i) {
        int f4 = t + i * 256;
        int r = f4 >> 4, c4 = (f4 & 15) * 4;
        float4 u4 = *(const float4*)&acc[(size_t)(i0 + r) * DD + c4];
        float4 v4 = *(const float4*)&acc[(size_t)(BU + j0 + r) * DD + c4];
        Us[r][c4 + 0] = u4.x; Us[r][c4 + 1] = u4.y;
        Us[r][c4 + 2] = u4.z; Us[r][c4 + 3] = u4.w;
        Is[r][c4 + 0] = v4.x; Is[r][c4 + 1] = v4.y;
        Is[r][c4 + 2] = v4.z; Is[r][c4 + 3] = v4.w;
    }
    __syncthreads();
    int tx = t & 15, ty = t >> 4;
    float s[4][4];
#pragma unroll
    for (int i = 0; i < 4; ++i)
#pragma unroll
        for (int j = 0; j < 4; ++j) s[i][j] = 0.f;
    for (int k = 0; k < 64; ++k) {
        float u[4], v[4];
#pragma unroll
        for (int i = 0; i < 4; ++i) u[i] = Us[ty * 4 + i][k];
#pragma unroll
        for (int j = 0; j < 4; ++j) v[j] = Is[tx * 4 + j][k];
#pragma unroll
        for (int i = 0; i < 4; ++i)
#pragma unroll
            for (int j = 0; j < 4; ++j) s[i][j] += u[i] * v[j];
    }
#pragma unroll
    for (int i = 0; i < 4; ++i) {
        float4 o;
        o.x = 1.f / (1.f + expf(-s[i][0] * 0.0625f));
        o.y = 1.f / (1.f + expf(-s[i][1] * 0.0625f));
        o.z = 1.f / (1.f + expf(-s[i][2] * 0.0625f));
        o.w = 1.f / (1.f + expf(-s[i][3] * 0.0625f));
        *(float4*)&out[(size_t)(i0 + ty * 4 + i) * BI + j0 + tx * 4] = o;
    }
}

// ================= launch =================

extern "C" void kernel_launch(void* const* d_in, const int* in_sizes, int n_in,
                              void* d_out, int out_size, void* d_ws, size_t ws_size,
                              hipStream_t stream) {
    const int*   users    = (const int*)d_in[0];
    const int*   items    = (const int*)d_in[1];
    const float* user_emb = (const float*)d_in[2];
    const float* item_emb = (const float*)d_in[3];
    const float* Wp       = (const float*)d_in[4];
    const float* bp       = (const float*)d_in[5];
    const int*   src      = (const int*)d_in[6];
    const int*   dst      = (const int*)d_in[7];
    const float* adj      = (const float*)d_in[9];

    int BU = in_sizes[0];
    int BI = in_sizes[1];
    int NU = in_sizes[2] / DD;
    int NI = in_sizes[3] / DD;
    int Nn = NU + NI;
    int E  = in_sizes[6];
    int EH = E / 2;
    int M  = Nn + 1;
    int Mp = (M + 3) & ~3;

    // ---- workspace (16B-aligned blocks first) ----
    u32*   tabA   = (u32*)d_ws;                              // Nn*32
    u32*   tabB   = tabA + (size_t)Nn * 32;                  // Nn*32
    int2*  ent    = (int2*)(tabB + (size_t)Nn * 32);         // E
    int*   cidx   = (int*)(ent + E);                         // EH
    float* norms  = (float*)(cidx + EH);                     // Nn
    float* rsA    = norms + Nn;                              // Nn
    float* rsB    = rsA + Nn;                                // Nn
    float* cosc   = rsB + Nn;                                // EH
    float* memc   = cosc + EH;                               // E
    float* acc    = memc + E;                                // (BU+BI)*64
    int*   deg    = (int*)(acc + (size_t)(BU + BI) * DD);    // Mp
    int*   rp     = deg + Mp;                                // Mp
    int*   rank   = rp + Mp;                                 // E
    int*   partial= rank + E;                                // 256

    int eb  = (E + 255) / 256;
    int ehb = (EH + 255) / 256;
    int nc  = (M + 1023) / 1024;

    // ---- CSR build ----
    hipMemsetAsync(deg, 0, sizeof(int) * (size_t)M, stream);
    hist_k<<<eb, 256, 0, stream>>>(src, deg, rank, E);
    scan1_k<<<nc, 256, 0, stream>>>(deg, rp, partial, M);
    scan2_k<<<1, 256, 0, stream>>>(partial, nc);
    scan3_k<<<(M + 255) / 256, 256, 0, stream>>>(rp, partial, M);
    scatter_k<<<ehb, 256, 0, stream>>>(src, dst, adj, rp, rank, ent, cidx, EH);

    // ---- bf16 table + norms + rsA zero + acc init (one launch) ----
    int cvtBlocks = (Nn * 4 + 255) / 256;
    int selBlocks = ((BU + BI) * 4 + 255) / 256;
    cvt_fused_k<<<cvtBlocks + selBlocks, 256, 0, stream>>>(user_emb, item_emb, users,
                                                           items, tabA, norms, rsA, acc,
                                                           NU, Nn, BU, BI, cvtBlocks);

    int cosBlocks = (NU * 4 + 255) / 256;
    int nBlocks   = (Nn * 4 + 255) / 256;

    // layer 0
    cos_acc_k<<<cosBlocks, 256, 0, stream>>>(tabA, norms, rp, ent, cosc, rsA,
                                             users, items, acc, NU, BU, BI, cosBlocks);
    spmm_fused_k<<<nBlocks, 256, 0, stream>>>(tabA, rp, ent, cidx, cosc, rsA, Wp, bp,
                                              memc, 1, tabB, norms, rsB, NU, EH, Nn);
    // layer 1 (cos + piggybacked acc_upd of tabB)
    cos_acc_k<<<cosBlocks + selBlocks, 256, 0, stream>>>(tabB, norms, rp, ent, cosc, rsB,
                                                         users, items, acc, NU, BU, BI,
                                                         cosBlocks);
    spmm_fused_k<<<nBlocks, 256, 0, stream>>>(tabB, rp, ent, cidx, cosc, rsB, Wp, bp,
                                              memc, 0, tabA, norms, rsA, NU, EH, Nn);
    // layer 2 (cos + piggybacked acc_upd of tabA)
    cos_acc_k<<<cosBlocks + selBlocks, 256, 0, stream>>>(tabA, norms, rp, ent, cosc, rsA,
                                                         users, items, acc, NU, BU, BI,
                                                         cosBlocks);
    sel_spmm_k<<<selBlocks, 256, 0, stream>>>(tabA, rp, ent, cidx, cosc, rsA, Wp, bp,
                                              memc, users, items, acc, BU, BI, NU, EH);

    dim3 grid(BI / 64, BU / 64);
    final_gemm_k<<<grid, 256, 0, stream>>>(acc, (float*)d_out, BU, BI);
}